// Round 14
// baseline (362.130 us; speedup 1.0000x reference)
//
#include <hip/hip_runtime.h>

// GCN: 2-layer GraphConv, N=100000, E=1600000, 128 -> 128 -> 40 (fp32).
// Round 23: MEASUREMENT ROUND. Pipeline byte-identical to R22 (272.8us best),
// but pass2 and gather2 are each launched 3x (both idempotent: pure
// recomputation, no global RMW). dTotal = 2*(pass2 + gather2) exposes the
// hidden kernels' cost; partconv = rest. Decision rule pre-committed in
// session notes. Intentional regression; R22 is banked.
constexpr int NN   = 100000;
constexpr int NE   = 1600000;
constexpr int INF  = 128;
constexpr int NC   = 40;
constexpr int HPAD = 64;                       // hwb padded row (bf16)

constexpr int BKSH = 9;                        // 512 nodes per coarse bucket
constexpr int NBK  = (NN + 511) / 512;         // 196 buckets
constexpr int CAPB = 10240;                    // fixed records per bucket
constexpr int EPB  = 4096;                     // edges per partition block
constexpr int PBLK = (NE + EPB - 1) / EPB;     // 391
constexpr int CVB  = 6250;                     // convert blocks (NN*128/8 / 256)
constexpr int ATS  = 136;                      // At LDS row stride (shorts)

typedef __attribute__((ext_vector_type(8))) short short8;
typedef __attribute__((ext_vector_type(4))) float f32x4;

__device__ __forceinline__ float bflo(unsigned int u) { return __uint_as_float(u << 16); }
__device__ __forceinline__ float bfhi(unsigned int u) { return __uint_as_float(u & 0xffff0000u); }
__device__ __forceinline__ unsigned short f2bf(float f) {          // RNE
    unsigned int u = __float_as_uint(f);
    return (unsigned short)((u + 0x7fffu + ((u >> 16) & 1u)) >> 16);
}
__device__ __forceinline__ unsigned int pack2(float a, float b) {
    return (unsigned int)f2bf(a) | ((unsigned int)f2bf(b) << 16);
}

// blocks 0..PBLK-1: dual partition into fixed-capacity buckets.
// blocks PBLK..PBLK+CVB-1: x (fp32) -> xh (bf16).
// last two blocks: W1 / W2 transpose -> bf16.
__global__ __launch_bounds__(256) void partconv_kernel(const int* __restrict__ src,
                                                       const int* __restrict__ dst,
                                                       int* __restrict__ curD_g,
                                                       int* __restrict__ curS_g,
                                                       int* __restrict__ epartsD,
                                                       unsigned short* __restrict__ epartsS,
                                                       const float* __restrict__ x,
                                                       unsigned short* __restrict__ xh,
                                                       const float* __restrict__ W1,
                                                       const float* __restrict__ W2,
                                                       unsigned short* __restrict__ w1t,
                                                       unsigned short* __restrict__ w2t) {
    const int tid = threadIdx.x;
    if (blockIdx.x >= PBLK) {
        int cb = blockIdx.x - PBLK;
        if (cb < CVB) {                          // ---- x convert ----
            int j = cb * 256 + tid;              // uint4 index, N*128/8 = 1.6M
            float4 v0 = ((const float4*)x)[2 * j];
            float4 v1 = ((const float4*)x)[2 * j + 1];
            uint4 o;
            o.x = pack2(v0.x, v0.y);
            o.y = pack2(v0.z, v0.w);
            o.z = pack2(v1.x, v1.y);
            o.w = pack2(v1.z, v1.w);
            ((uint4*)xh)[j] = o;
        } else if (cb == CVB) {                  // ---- W1 transpose ----
            for (int i = tid; i < 128 * 128; i += 256) {
                int k = i >> 7, n = i & 127;
                w1t[n * 128 + k] = f2bf(W1[i]);
            }
        } else {                                 // ---- W2 transpose ----
            for (int i = tid; i < 48 * 128; i += 256) {
                int n = i >> 7, k = i & 127;
                w2t[i] = f2bf((n < NC) ? W2[k * NC + n] : 0.f);
            }
        }
        return;
    }
    // ---- partition part ----
    __shared__ int sc[256];
    __shared__ int cntD[NBK], gadjD[NBK], curD[NBK];
    __shared__ int cntS[NBK], gadjS[NBK], curS[NBK];
    __shared__ int stageD[EPB];
    __shared__ unsigned short stageS[EPB];
    __shared__ unsigned char bidD[EPB];
    __shared__ unsigned char bidS[EPB];
    const int e0 = blockIdx.x * EPB;
    const int total = min(EPB, NE - e0);

    for (int i = tid; i < NBK; i += 256) { cntD[i] = 0; cntS[i] = 0; }
    __syncthreads();
    // phase A: count per bucket (both keys)
    for (int i = tid; i < total; i += 256) {
        atomicAdd(&cntD[dst[e0 + i] >> BKSH], 1);
        atomicAdd(&cntS[src[e0 + i] >> BKSH], 1);
    }
    __syncthreads();
    // exclusive scans of cntD, cntS; reserve global ranges (base = b*CAPB)
    {
        int v = (tid < NBK) ? cntD[tid] : 0;
        sc[tid] = v;
        __syncthreads();
        for (int off = 1; off < 256; off <<= 1) {
            int t = (tid >= off) ? sc[tid - off] : 0;
            __syncthreads();
            sc[tid] += t;
            __syncthreads();
        }
        if (tid < NBK) {
            int excl = sc[tid] - v;
            curD[tid] = excl;
            int g = (v > 0) ? atomicAdd(&curD_g[tid], v) : 0;
            gadjD[tid] = tid * CAPB + g - excl;
        }
        __syncthreads();
        v = (tid < NBK) ? cntS[tid] : 0;
        sc[tid] = v;
        __syncthreads();
        for (int off = 1; off < 256; off <<= 1) {
            int t = (tid >= off) ? sc[tid - off] : 0;
            __syncthreads();
            sc[tid] += t;
            __syncthreads();
        }
        if (tid < NBK) {
            int excl = sc[tid] - v;
            curS[tid] = excl;
            int g = (v > 0) ? atomicAdd(&curS_g[tid], v) : 0;
            gadjS[tid] = tid * CAPB + g - excl;
        }
    }
    __syncthreads();
    // phase B: re-read edges, stage grouped by bucket (both keys)
    for (int i = tid; i < total; i += 256) {
        int s = src[e0 + i];
        int d = dst[e0 + i];
        int bD = d >> BKSH;
        int offD = atomicAdd(&curD[bD], 1);
        stageD[offD] = s | ((d - (bD << BKSH)) << 17);
        bidD[offD] = (unsigned char)bD;
        int bS = s >> BKSH;
        int offS = atomicAdd(&curS[bS], 1);
        stageS[offS] = (unsigned short)(s - (bS << BKSH));
        bidS[offS] = (unsigned char)bS;
    }
    __syncthreads();
    // dumps: consecutive j within a bucket-run -> consecutive global addresses
    for (int j = tid; j < total; j += 256) {
        int b = bidD[j];
        epartsD[gadjD[b] + j] = stageD[j];
    }
    for (int j = tid; j < total; j += 256) {
        int b = bidS[j];
        epartsS[gadjS[b] + j] = stageS[j];
    }
}

// per-bucket (1024 threads): dst CSR (hist+scan+LDS scatter -> row_beg/
// row_end, dstn, esrc) AND src out-degree hist -> srcn. Bases b*CAPB;
// counts from cursors. Scan is 512-wide; all threads execute barriers.
// IDEMPOTENT (no global RMW) — safe to launch multiple times.
__global__ __launch_bounds__(1024) void pass2_kernel(const int* __restrict__ epartsD,
                                                     const unsigned short* __restrict__ epartsS,
                                                     const int* __restrict__ curD_g,
                                                     const int* __restrict__ curS_g,
                                                     int* __restrict__ row_beg,
                                                     int* __restrict__ row_end,
                                                     int* __restrict__ esrc,
                                                     float* __restrict__ srcn,
                                                     float* __restrict__ dstn) {
    __shared__ int hist[512];
    __shared__ int cur[512];
    __shared__ int histS[512];
    __shared__ int lesrc[CAPB];
    const int tid = threadIdx.x;
    const int b = blockIdx.x;

    const int base  = b * CAPB;
    const int cnt   = curD_g[b];
    const int cntS  = curS_g[b];
    const int n0 = b << BKSH;
    const int nloc = min(512, NN - n0);

    if (tid < 512) { hist[tid] = 0; histS[tid] = 0; }
    __syncthreads();
    for (int j = tid; j < cnt; j += 1024)
        atomicAdd(&hist[epartsD[base + j] >> 17], 1);
    for (int j = tid; j < cntS; j += 1024)
        atomicAdd(&histS[(int)epartsS[base + j]], 1);
    __syncthreads();
    int myc  = (tid < 512) ? hist[tid] : 0;
    int mycS = (tid < 512) ? histS[tid] : 0;
    for (int off = 1; off < 512; off <<= 1) {
        int t = (tid < 512 && tid >= off) ? hist[tid - off] : 0;
        __syncthreads();
        if (tid < 512) hist[tid] += t;
        __syncthreads();
    }
    if (tid < 512) {
        int excl = hist[tid] - myc;
        cur[tid] = excl;
        if (tid < nloc) {
            int g = n0 + tid;
            row_beg[g] = base + excl;
            row_end[g] = base + excl + myc;
            dstn[g] = rsqrtf(fmaxf((float)myc, 1.0f));    // dst_norm (in-degree)
            srcn[g] = rsqrtf(fmaxf((float)mycS, 1.0f));   // src_norm (out-degree)
        }
    }
    __syncthreads();
    for (int j = tid; j < cnt; j += 1024) {
        int rec = epartsD[base + j];
        int pos = atomicAdd(&cur[rec >> 17], 1);
        lesrc[pos] = rec & 0x1FFFF;
    }
    __syncthreads();
    for (int j = tid; j < cnt; j += 1024) esrc[base + j] = lesrc[j];
}

// Fused gather1 + GEMM1 + GEMM2. 32 nodes/block, 4 waves x 8 nodes serial
// (single-stream gather body, 28 VGPR), (256,8), 3125 blocks.
__global__ __launch_bounds__(256, 8) void fused_kernel(const int* __restrict__ row_beg,
                                                       const int* __restrict__ row_end,
                                                       const int* __restrict__ esrc,
                                                       const unsigned short* __restrict__ xh,
                                                       const float* __restrict__ srcn,
                                                       const unsigned short* __restrict__ w1t,
                                                       const unsigned short* __restrict__ w2t,
                                                       const float* __restrict__ b1,
                                                       const float* __restrict__ dstn,
                                                       unsigned short* __restrict__ hwb) {
    __shared__ unsigned short At[32 * ATS];    // 8.5 KB: agg tile, then h tile
    __shared__ float dn[32], sn[32], b1l[128];
    const int tid  = threadIdx.x;
    const int r0   = blockIdx.x * 32;
    const int wv   = tid >> 6;
    const int lane = tid & 63;

    if (tid < 32) {
        int r = r0 + tid;
        dn[tid] = (r < NN) ? dstn[r] : 0.f;
        sn[tid] = (r < NN) ? srcn[r] : 0.f;
    }
    if (tid >= 64 && tid < 192) b1l[tid - 64] = b1[tid - 64];
    __syncthreads();

    // ---- phase 1: gather 8 nodes serially (single-stream body) ----
    const int quad = lane >> 4;       // edge-slot group 0..3
    const int l16  = lane & 15;       // uint4 index within 256 B row
    for (int i = 0; i < 8; ++i) {
        const int node = r0 + wv * 8 + i;
        float a0 = 0.f, a1 = 0.f, a2 = 0.f, a3 = 0.f;
        float a4 = 0.f, a5 = 0.f, a6 = 0.f, a7 = 0.f;
        if (node < NN) {
            int beg = __builtin_amdgcn_readfirstlane(row_beg[node]);
            int end = __builtin_amdgcn_readfirstlane(row_end[node]);
            for (int e = beg; e < end; e += 16) {
                const int rem = end - e;
                int s[4];
#pragma unroll
                for (int t = 0; t < 4; ++t) {
                    int slot = t * 4 + quad;
                    s[t] = esrc[(slot < rem) ? (e + slot) : beg];
                }
                float n[4];
                uint4 u[4];
#pragma unroll
                for (int t = 0; t < 4; ++t) {
                    int slot = t * 4 + quad;
                    n[t] = (slot < rem) ? srcn[s[t]] : 0.f;
                    u[t] = ((const uint4*)(xh + (size_t)s[t] * INF))[l16];
                }
#pragma unroll
                for (int t = 0; t < 4; ++t) {
                    a0 += bflo(u[t].x) * n[t]; a1 += bfhi(u[t].x) * n[t];
                    a2 += bflo(u[t].y) * n[t]; a3 += bfhi(u[t].y) * n[t];
                    a4 += bflo(u[t].z) * n[t]; a5 += bfhi(u[t].z) * n[t];
                    a6 += bflo(u[t].w) * n[t]; a7 += bfhi(u[t].w) * n[t];
                }
            }
        }
        a0 += __shfl_down(a0, 32); a1 += __shfl_down(a1, 32);
        a2 += __shfl_down(a2, 32); a3 += __shfl_down(a3, 32);
        a4 += __shfl_down(a4, 32); a5 += __shfl_down(a5, 32);
        a6 += __shfl_down(a6, 32); a7 += __shfl_down(a7, 32);
        a0 += __shfl_down(a0, 16); a1 += __shfl_down(a1, 16);
        a2 += __shfl_down(a2, 16); a3 += __shfl_down(a3, 16);
        a4 += __shfl_down(a4, 16); a5 += __shfl_down(a5, 16);
        a6 += __shfl_down(a6, 16); a7 += __shfl_down(a7, 16);
        if (lane < 16) {
            uint4 o;
            o.x = pack2(a0, a1);
            o.y = pack2(a2, a3);
            o.z = pack2(a4, a5);
            o.w = pack2(a6, a7);
            *(uint4*)&At[(wv * 8 + i) * ATS + l16 * 8] = o;
        }
    }
    __syncthreads();   // cross-wave: GEMM reads rows gathered by other waves

    // ---- phase 2: MFMA GEMM1 (+relu), split (row-tile, nt-half) ----
    const int lrow  = lane & 15;
    const int lquad = lane >> 4;
    const int rt    = wv >> 1;            // row-tile 0 (rows 0-15) / 1 (16-31)
    const int ntB   = (wv & 1) * 4;       // nt-half 0-3 / 4-7

    // ALL waves snapshot their A-frags to registers before ANY h write.
    short8 afrag[4];
#pragma unroll
    for (int ks = 0; ks < 4; ++ks)
        afrag[ks] = *(const short8*)&At[(rt * 16 + lrow) * ATS + ks * 32 + lquad * 8];
    __syncthreads();   // agg reads complete before h overwrites At

    float hreg[4][4];
#pragma unroll
    for (int nt2 = 0; nt2 < 4; ++nt2) {
        f32x4 acc = {0.f, 0.f, 0.f, 0.f};
#pragma unroll
        for (int ks = 0; ks < 4; ++ks) {
            short8 bfr = *(const short8*)&w1t[((ntB + nt2) * 16 + lrow) * 128 + ks * 32 + lquad * 8];
            acc = __builtin_amdgcn_mfma_f32_16x16x32_bf16(afrag[ks], bfr, acc, 0, 0, 0);
        }
#pragma unroll
        for (int i = 0; i < 4; ++i) hreg[nt2][i] = acc[i];
    }
#pragma unroll
    for (int nt2 = 0; nt2 < 4; ++nt2) {
        int col = (ntB + nt2) * 16 + lrow;
        float bb = b1l[col];
#pragma unroll
        for (int i = 0; i < 4; ++i) {
            int row = rt * 16 + lquad * 4 + i;
            At[row * ATS + col] = f2bf(fmaxf(hreg[nt2][i] * dn[row] + bb, 0.f));
        }
    }
    __syncthreads();   // cross-wave: GEMM2 reads h cols written by nt-half peer

    // ---- GEMM2 on waves 0/2 (row-tile wv>>1) ----
    if ((wv & 1) == 0) {
        short8 hf[4];
#pragma unroll
        for (int ks = 0; ks < 4; ++ks)
            hf[ks] = *(const short8*)&At[(rt * 16 + lrow) * ATS + ks * 32 + lquad * 8];
#pragma unroll
        for (int nt = 0; nt < 3; ++nt) {
            f32x4 acc = {0.f, 0.f, 0.f, 0.f};
#pragma unroll
            for (int ks = 0; ks < 4; ++ks) {
                short8 bfr = *(const short8*)&w2t[(nt * 16 + lrow) * 128 + ks * 32 + lquad * 8];
                acc = __builtin_amdgcn_mfma_f32_16x16x32_bf16(hf[ks], bfr, acc, 0, 0, 0);
            }
            int col = nt * 16 + lrow;
            if (col < NC) {
#pragma unroll
                for (int i = 0; i < 4; ++i) {
                    int row = rt * 16 + lquad * 4 + i;
                    int grow = r0 + row;
                    if (grow < NN)
                        hwb[(size_t)grow * HPAD + col] = f2bf(acc[i] * sn[row]);
                }
            }
        }
    }
}

// one wave per node, hwb rows padded to 128 B. lane = g*8+j (g<8, j<8):
// 8 edge slots per step, uint4 reads; predicated 32-edge batches.
// IDEMPOTENT (pure writes of `out`) — safe to launch multiple times.
__global__ __launch_bounds__(256) void gather2_kernel(const int* __restrict__ row_beg,
                                                      const int* __restrict__ row_end,
                                                      const int* __restrict__ esrc,
                                                      const unsigned short* __restrict__ hwb,
                                                      const float* __restrict__ dst_norm,
                                                      const float* __restrict__ b2,
                                                      float* __restrict__ out) {
    int node = (blockIdx.x * blockDim.x + threadIdx.x) >> 6;
    int lane = threadIdx.x & 63;
    if (node >= NN) return;
    int beg = __builtin_amdgcn_readfirstlane(row_beg[node]);
    int end = __builtin_amdgcn_readfirstlane(row_end[node]);
    const int g = lane >> 3;          // edge slot 0..7
    const int j = lane & 7;           // uint4 index within 128 B row
    float a0 = 0.f, a1 = 0.f, a2 = 0.f, a3 = 0.f;
    float a4 = 0.f, a5 = 0.f, a6 = 0.f, a7 = 0.f;
    for (int e = beg; e < end; e += 32) {
        const int rem = end - e;
        int s[4];
        float m[4];
#pragma unroll
        for (int q = 0; q < 4; ++q) {
            int slot = q * 8 + g;
            bool v = (slot < rem);
            s[q] = esrc[v ? (e + slot) : beg];
            m[q] = v ? 1.f : 0.f;
        }
        uint4 u[4];
#pragma unroll
        for (int q = 0; q < 4; ++q)
            u[q] = ((const uint4*)(hwb + (size_t)s[q] * HPAD))[j];
#pragma unroll
        for (int q = 0; q < 4; ++q) {
            a0 += bflo(u[q].x) * m[q]; a1 += bfhi(u[q].x) * m[q];
            a2 += bflo(u[q].y) * m[q]; a3 += bfhi(u[q].y) * m[q];
            a4 += bflo(u[q].z) * m[q]; a5 += bfhi(u[q].z) * m[q];
            a6 += bflo(u[q].w) * m[q]; a7 += bfhi(u[q].w) * m[q];
        }
    }
    // reduce over the 8 g-groups (same j): lanes l <- l+32, l+16, l+8
    a0 += __shfl_down(a0, 32); a1 += __shfl_down(a1, 32);
    a2 += __shfl_down(a2, 32); a3 += __shfl_down(a3, 32);
    a4 += __shfl_down(a4, 32); a5 += __shfl_down(a5, 32);
    a6 += __shfl_down(a6, 32); a7 += __shfl_down(a7, 32);
    a0 += __shfl_down(a0, 16); a1 += __shfl_down(a1, 16);
    a2 += __shfl_down(a2, 16); a3 += __shfl_down(a3, 16);
    a4 += __shfl_down(a4, 16); a5 += __shfl_down(a5, 16);
    a6 += __shfl_down(a6, 16); a7 += __shfl_down(a7, 16);
    a0 += __shfl_down(a0, 8);  a1 += __shfl_down(a1, 8);
    a2 += __shfl_down(a2, 8);  a3 += __shfl_down(a3, 8);
    a4 += __shfl_down(a4, 8);  a5 += __shfl_down(a5, 8);
    a6 += __shfl_down(a6, 8);  a7 += __shfl_down(a7, 8);
    if (lane < 5) {                    // j = lane, g == 0: cols 8j..8j+7
        float dnv = dst_norm[node];
        float4 bb0 = ((const float4*)b2)[2 * lane];
        float4 bb1 = ((const float4*)b2)[2 * lane + 1];
        float4 o0, o1;
        o0.x = a0 * dnv + bb0.x;
        o0.y = a1 * dnv + bb0.y;
        o0.z = a2 * dnv + bb0.z;
        o0.w = a3 * dnv + bb0.w;
        o1.x = a4 * dnv + bb1.x;
        o1.y = a5 * dnv + bb1.y;
        o1.z = a6 * dnv + bb1.z;
        o1.w = a7 * dnv + bb1.w;
        float4* op = (float4*)(out + (size_t)node * NC);
        op[2 * lane]     = o0;
        op[2 * lane + 1] = o1;
    }
}

extern "C" void kernel_launch(void* const* d_in, const int* in_sizes, int n_in,
                              void* d_out, int out_size, void* d_ws, size_t ws_size,
                              hipStream_t stream) {
    const float* x   = (const float*)d_in[0];
    const float* W1  = (const float*)d_in[1];
    const float* b1  = (const float*)d_in[2];
    const float* W2  = (const float*)d_in[3];
    const float* b2  = (const float*)d_in[4];
    const int*   src = (const int*)d_in[5];
    const int*   dst = (const int*)d_in[6];
    float* out = (float*)d_out;

    // workspace (4B units):
    // srcn[NN] | curDg[256] | curSg[256] | row_beg[NN] | row_end[NN] |
    // dstn[NN] | esrc[NBK*CAPB] | pad | xh[NN*64] | w1t[8192] | w2t[3072] |
    // hwb[NN*32]  (bf16 NN x 64)
    float* srcn = (float*)d_ws;
    int* curDg = (int*)(srcn + NN);
    int* curSg = curDg + 256;
    int* row_beg = curSg + 256;
    int* row_end = row_beg + NN;
    float* dstn  = (float*)(row_end + NN);
    int* esrc    = (int*)(dstn + NN);
    size_t ofs = (size_t)NN + 512 + 3 * (size_t)NN + (size_t)NBK * CAPB;
    ofs = (ofs + 3) & ~(size_t)3;                 // 16B align
    unsigned short* xh   = (unsigned short*)((float*)d_ws + ofs);
    unsigned short* w1t  = xh + (size_t)NN * INF;
    unsigned short* w2t  = w1t + 128 * 128;
    unsigned short* hwb  = w2t + 48 * 128;

    // edge-record scratch in d_out (12 MB of 16 MB) — dead before gather2 writes
    int* epartsD = (int*)d_out;                                 // 8.03 MB
    unsigned short* epartsS = (unsigned short*)(epartsD + (size_t)NBK * CAPB);  // 4.01 MB

    hipMemsetAsync(curDg, 0, 512 * sizeof(int), stream);   // curDg | curSg

    partconv_kernel<<<PBLK + CVB + 2, 256, 0, stream>>>(src, dst, curDg, curSg,
                                                        epartsD, epartsS,
                                                        x, xh, W1, W2, w1t, w2t);
    // pass2 x3 (idempotent) — measurement duplicates
    pass2_kernel<<<NBK, 1024, 0, stream>>>(epartsD, epartsS, curDg, curSg,
                                           row_beg, row_end, esrc, srcn, dstn);
    pass2_kernel<<<NBK, 1024, 0, stream>>>(epartsD, epartsS, curDg, curSg,
                                           row_beg, row_end, esrc, srcn, dstn);
    pass2_kernel<<<NBK, 1024, 0, stream>>>(epartsD, epartsS, curDg, curSg,
                                           row_beg, row_end, esrc, srcn, dstn);
    fused_kernel<<<(NN + 31) / 32, 256, 0, stream>>>(row_beg, row_end, esrc, xh,
                                                     srcn, w1t, w2t, b1, dstn, hwb);
    // gather2 x3 (idempotent) — measurement duplicates
    gather2_kernel<<<(NN * 64 + 255) / 256, 256, 0, stream>>>(row_beg, row_end,
                                                              esrc, hwb,
                                                              dstn, b2, out);
    gather2_kernel<<<(NN * 64 + 255) / 256, 256, 0, stream>>>(row_beg, row_end,
                                                              esrc, hwb,
                                                              dstn, b2, out);
    gather2_kernel<<<(NN * 64 + 255) / 256, 256, 0, stream>>>(row_beg, row_end,
                                                              esrc, hwb,
                                                              dstn, b2, out);
}

// Round 15
// 263.242 us; speedup vs baseline: 1.3757x; 1.3757x over previous
//
#include <hip/hip_runtime.h>

// GCN: 2-layer GraphConv, N=100000, E=1600000, 128 -> 128 -> 40 (fp32).
// Round 24: build rebalance (R23 measurement: pass2+gather2 ~45us, partconv
// ~70-90us, gaps ~20-45us).
//   part:     partition ONLY. (s,d) stashed in registers between count and
//             stage phases (no 2nd edge read); wave-level shfl scans replace
//             256-wide Hillis-Steele (~30 barriers -> 2).
//   pass2conv: pass2 (196 x 1024) + x->xh convert + W1/W2 transpose blocks —
//             convert rides pass2's idle CUs (pass2 alone = 0.76 blocks/CU).
//   fused/gather2: unchanged from R22 (272.8us best).
constexpr int NN   = 100000;
constexpr int NE   = 1600000;
constexpr int INF  = 128;
constexpr int NC   = 40;
constexpr int HPAD = 64;                       // hwb padded row (bf16)

constexpr int BKSH = 9;                        // 512 nodes per coarse bucket
constexpr int NBK  = (NN + 511) / 512;         // 196 buckets
constexpr int CAPB = 10240;                    // fixed records per bucket
constexpr int EPB  = 4096;                     // edges per partition block
constexpr int PBLK = (NE + EPB - 1) / EPB;     // 391
constexpr int CVB4 = 1563;                     // convert blocks (1.6M uint4 / 1024)
constexpr int ATS  = 136;                      // At LDS row stride (shorts)

typedef __attribute__((ext_vector_type(8))) short short8;
typedef __attribute__((ext_vector_type(4))) float f32x4;

__device__ __forceinline__ float bflo(unsigned int u) { return __uint_as_float(u << 16); }
__device__ __forceinline__ float bfhi(unsigned int u) { return __uint_as_float(u & 0xffff0000u); }
__device__ __forceinline__ unsigned short f2bf(float f) {          // RNE
    unsigned int u = __float_as_uint(f);
    return (unsigned short)((u + 0x7fffu + ((u >> 16) & 1u)) >> 16);
}
__device__ __forceinline__ unsigned int pack2(float a, float b) {
    return (unsigned int)f2bf(a) | ((unsigned int)f2bf(b) << 16);
}

// partition only: dual counting-sort into fixed-capacity buckets.
// Phase A counts AND stashes (s,d) in registers (static-indexed, unrolled);
// wave-level scans (2 barriers total); phase B stages from registers;
// coalesced bucket-run dumps.
__global__ __launch_bounds__(256) void part_kernel(const int* __restrict__ src,
                                                   const int* __restrict__ dst,
                                                   int* __restrict__ curD_g,
                                                   int* __restrict__ curS_g,
                                                   int* __restrict__ epartsD,
                                                   unsigned short* __restrict__ epartsS) {
    __shared__ int cntD[NBK], gadjD[NBK], curD[NBK];
    __shared__ int cntS[NBK], gadjS[NBK], curS[NBK];
    __shared__ int stageD[EPB];
    __shared__ unsigned short stageS[EPB];
    __shared__ unsigned char bidD[EPB];
    __shared__ unsigned char bidS[EPB];
    __shared__ int wtot[8];
    const int tid = threadIdx.x;
    const int e0 = blockIdx.x * EPB;
    const int total = min(EPB, NE - e0);

    for (int i = tid; i < NBK; i += 256) { cntD[i] = 0; cntS[i] = 0; }
    __syncthreads();
    // phase A: count per bucket + stash edges in registers
    int se[16], de[16];
#pragma unroll
    for (int k = 0; k < 16; ++k) {
        int i = tid + k * 256;
        se[k] = 0; de[k] = 0;
        if (i < total) {
            int s = src[e0 + i];
            int d = dst[e0 + i];
            se[k] = s; de[k] = d;
            atomicAdd(&cntD[d >> BKSH], 1);
            atomicAdd(&cntS[s >> BKSH], 1);
        }
    }
    __syncthreads();
    // wave-level exclusive scans of cntD/cntS; reserve global ranges
    {
        const int lane = tid & 63;
        const int w = tid >> 6;
        int vD = (tid < NBK) ? cntD[tid] : 0;
        int vS = (tid < NBK) ? cntS[tid] : 0;
        int xD = vD, xS = vS;
#pragma unroll
        for (int off = 1; off < 64; off <<= 1) {
            int tD = __shfl_up(xD, off);
            int tS = __shfl_up(xS, off);
            if (lane >= off) { xD += tD; xS += tS; }
        }
        if (lane == 63) { wtot[w] = xD; wtot[4 + w] = xS; }
        __syncthreads();
        int pD = 0, pS = 0;
        for (int i = 0; i < w; ++i) { pD += wtot[i]; pS += wtot[4 + i]; }
        if (tid < NBK) {
            int exclD = xD + pD - vD;
            curD[tid] = exclD;
            int g = (vD > 0) ? atomicAdd(&curD_g[tid], vD) : 0;
            gadjD[tid] = tid * CAPB + g - exclD;
            int exclS = xS + pS - vS;
            curS[tid] = exclS;
            int g2 = (vS > 0) ? atomicAdd(&curS_g[tid], vS) : 0;
            gadjS[tid] = tid * CAPB + g2 - exclS;
        }
    }
    __syncthreads();
    // phase B: stage grouped by bucket, from registers
#pragma unroll
    for (int k = 0; k < 16; ++k) {
        int i = tid + k * 256;
        if (i < total) {
            int s = se[k];
            int d = de[k];
            int bD = d >> BKSH;
            int offD = atomicAdd(&curD[bD], 1);
            stageD[offD] = s | ((d - (bD << BKSH)) << 17);
            bidD[offD] = (unsigned char)bD;
            int bS = s >> BKSH;
            int offS = atomicAdd(&curS[bS], 1);
            stageS[offS] = (unsigned short)(s - (bS << BKSH));
            bidS[offS] = (unsigned char)bS;
        }
    }
    __syncthreads();
    // dumps: consecutive j within a bucket-run -> consecutive global addresses
    for (int j = tid; j < total; j += 256) {
        int b = bidD[j];
        epartsD[gadjD[b] + j] = stageD[j];
    }
    for (int j = tid; j < total; j += 256) {
        int b = bidS[j];
        epartsS[gadjS[b] + j] = stageS[j];
    }
}

// blocks 0..NBK-1 (1024 thr): pass2 — dst CSR (hist+scan+LDS scatter ->
// row_beg/row_end, dstn, esrc) AND src out-degree hist -> srcn.
// blocks NBK..NBK+CVB4-1: x (fp32) -> xh (bf16). Last two: W1/W2 transpose.
__global__ __launch_bounds__(1024) void pass2conv_kernel(const int* __restrict__ epartsD,
                                                         const unsigned short* __restrict__ epartsS,
                                                         const int* __restrict__ curD_g,
                                                         const int* __restrict__ curS_g,
                                                         int* __restrict__ row_beg,
                                                         int* __restrict__ row_end,
                                                         int* __restrict__ esrc,
                                                         float* __restrict__ srcn,
                                                         float* __restrict__ dstn,
                                                         const float* __restrict__ x,
                                                         unsigned short* __restrict__ xh,
                                                         const float* __restrict__ W1,
                                                         const float* __restrict__ W2,
                                                         unsigned short* __restrict__ w1t,
                                                         unsigned short* __restrict__ w2t) {
    const int tid = threadIdx.x;
    const int blk = blockIdx.x;
    if (blk >= NBK) {
        int cb = blk - NBK;
        if (cb < CVB4) {                         // ---- x convert ----
            int j = cb * 1024 + tid;             // uint4 index, N*128/8 = 1.6M
            if (j < NN * INF / 8) {
                float4 v0 = ((const float4*)x)[2 * j];
                float4 v1 = ((const float4*)x)[2 * j + 1];
                uint4 o;
                o.x = pack2(v0.x, v0.y);
                o.y = pack2(v0.z, v0.w);
                o.z = pack2(v1.x, v1.y);
                o.w = pack2(v1.z, v1.w);
                ((uint4*)xh)[j] = o;
            }
        } else if (cb == CVB4) {                 // ---- W1 transpose ----
            for (int i = tid; i < 128 * 128; i += 1024) {
                int k = i >> 7, n = i & 127;
                w1t[n * 128 + k] = f2bf(W1[i]);
            }
        } else {                                 // ---- W2 transpose ----
            for (int i = tid; i < 48 * 128; i += 1024) {
                int n = i >> 7, k = i & 127;
                w2t[i] = f2bf((n < NC) ? W2[k * NC + n] : 0.f);
            }
        }
        return;
    }
    __shared__ int hist[512];
    __shared__ int cur[512];
    __shared__ int histS[512];
    __shared__ int lesrc[CAPB];
    const int b = blk;

    const int base  = b * CAPB;
    const int cnt   = curD_g[b];
    const int cntS  = curS_g[b];
    const int n0 = b << BKSH;
    const int nloc = min(512, NN - n0);

    if (tid < 512) { hist[tid] = 0; histS[tid] = 0; }
    __syncthreads();
    for (int j = tid; j < cnt; j += 1024)
        atomicAdd(&hist[epartsD[base + j] >> 17], 1);
    for (int j = tid; j < cntS; j += 1024)
        atomicAdd(&histS[(int)epartsS[base + j]], 1);
    __syncthreads();
    int myc  = (tid < 512) ? hist[tid] : 0;
    int mycS = (tid < 512) ? histS[tid] : 0;
    for (int off = 1; off < 512; off <<= 1) {
        int t = (tid < 512 && tid >= off) ? hist[tid - off] : 0;
        __syncthreads();
        if (tid < 512) hist[tid] += t;
        __syncthreads();
    }
    if (tid < 512) {
        int excl = hist[tid] - myc;
        cur[tid] = excl;
        if (tid < nloc) {
            int g = n0 + tid;
            row_beg[g] = base + excl;
            row_end[g] = base + excl + myc;
            dstn[g] = rsqrtf(fmaxf((float)myc, 1.0f));    // dst_norm (in-degree)
            srcn[g] = rsqrtf(fmaxf((float)mycS, 1.0f));   // src_norm (out-degree)
        }
    }
    __syncthreads();
    for (int j = tid; j < cnt; j += 1024) {
        int rec = epartsD[base + j];
        int pos = atomicAdd(&cur[rec >> 17], 1);
        lesrc[pos] = rec & 0x1FFFF;
    }
    __syncthreads();
    for (int j = tid; j < cnt; j += 1024) esrc[base + j] = lesrc[j];
}

// Fused gather1 + GEMM1 + GEMM2. 32 nodes/block, 4 waves x 8 nodes serial
// (single-stream gather body, 28 VGPR), (256,8), 3125 blocks.
__global__ __launch_bounds__(256, 8) void fused_kernel(const int* __restrict__ row_beg,
                                                       const int* __restrict__ row_end,
                                                       const int* __restrict__ esrc,
                                                       const unsigned short* __restrict__ xh,
                                                       const float* __restrict__ srcn,
                                                       const unsigned short* __restrict__ w1t,
                                                       const unsigned short* __restrict__ w2t,
                                                       const float* __restrict__ b1,
                                                       const float* __restrict__ dstn,
                                                       unsigned short* __restrict__ hwb) {
    __shared__ unsigned short At[32 * ATS];    // 8.5 KB: agg tile, then h tile
    __shared__ float dn[32], sn[32], b1l[128];
    const int tid  = threadIdx.x;
    const int r0   = blockIdx.x * 32;
    const int wv   = tid >> 6;
    const int lane = tid & 63;

    if (tid < 32) {
        int r = r0 + tid;
        dn[tid] = (r < NN) ? dstn[r] : 0.f;
        sn[tid] = (r < NN) ? srcn[r] : 0.f;
    }
    if (tid >= 64 && tid < 192) b1l[tid - 64] = b1[tid - 64];
    __syncthreads();

    // ---- phase 1: gather 8 nodes serially (single-stream body) ----
    const int quad = lane >> 4;       // edge-slot group 0..3
    const int l16  = lane & 15;       // uint4 index within 256 B row
    for (int i = 0; i < 8; ++i) {
        const int node = r0 + wv * 8 + i;
        float a0 = 0.f, a1 = 0.f, a2 = 0.f, a3 = 0.f;
        float a4 = 0.f, a5 = 0.f, a6 = 0.f, a7 = 0.f;
        if (node < NN) {
            int beg = __builtin_amdgcn_readfirstlane(row_beg[node]);
            int end = __builtin_amdgcn_readfirstlane(row_end[node]);
            for (int e = beg; e < end; e += 16) {
                const int rem = end - e;
                int s[4];
#pragma unroll
                for (int t = 0; t < 4; ++t) {
                    int slot = t * 4 + quad;
                    s[t] = esrc[(slot < rem) ? (e + slot) : beg];
                }
                float n[4];
                uint4 u[4];
#pragma unroll
                for (int t = 0; t < 4; ++t) {
                    int slot = t * 4 + quad;
                    n[t] = (slot < rem) ? srcn[s[t]] : 0.f;
                    u[t] = ((const uint4*)(xh + (size_t)s[t] * INF))[l16];
                }
#pragma unroll
                for (int t = 0; t < 4; ++t) {
                    a0 += bflo(u[t].x) * n[t]; a1 += bfhi(u[t].x) * n[t];
                    a2 += bflo(u[t].y) * n[t]; a3 += bfhi(u[t].y) * n[t];
                    a4 += bflo(u[t].z) * n[t]; a5 += bfhi(u[t].z) * n[t];
                    a6 += bflo(u[t].w) * n[t]; a7 += bfhi(u[t].w) * n[t];
                }
            }
        }
        a0 += __shfl_down(a0, 32); a1 += __shfl_down(a1, 32);
        a2 += __shfl_down(a2, 32); a3 += __shfl_down(a3, 32);
        a4 += __shfl_down(a4, 32); a5 += __shfl_down(a5, 32);
        a6 += __shfl_down(a6, 32); a7 += __shfl_down(a7, 32);
        a0 += __shfl_down(a0, 16); a1 += __shfl_down(a1, 16);
        a2 += __shfl_down(a2, 16); a3 += __shfl_down(a3, 16);
        a4 += __shfl_down(a4, 16); a5 += __shfl_down(a5, 16);
        a6 += __shfl_down(a6, 16); a7 += __shfl_down(a7, 16);
        if (lane < 16) {
            uint4 o;
            o.x = pack2(a0, a1);
            o.y = pack2(a2, a3);
            o.z = pack2(a4, a5);
            o.w = pack2(a6, a7);
            *(uint4*)&At[(wv * 8 + i) * ATS + l16 * 8] = o;
        }
    }
    __syncthreads();   // cross-wave: GEMM reads rows gathered by other waves

    // ---- phase 2: MFMA GEMM1 (+relu), split (row-tile, nt-half) ----
    const int lrow  = lane & 15;
    const int lquad = lane >> 4;
    const int rt    = wv >> 1;            // row-tile 0 (rows 0-15) / 1 (16-31)
    const int ntB   = (wv & 1) * 4;       // nt-half 0-3 / 4-7

    // ALL waves snapshot their A-frags to registers before ANY h write.
    short8 afrag[4];
#pragma unroll
    for (int ks = 0; ks < 4; ++ks)
        afrag[ks] = *(const short8*)&At[(rt * 16 + lrow) * ATS + ks * 32 + lquad * 8];
    __syncthreads();   // agg reads complete before h overwrites At

    float hreg[4][4];
#pragma unroll
    for (int nt2 = 0; nt2 < 4; ++nt2) {
        f32x4 acc = {0.f, 0.f, 0.f, 0.f};
#pragma unroll
        for (int ks = 0; ks < 4; ++ks) {
            short8 bfr = *(const short8*)&w1t[((ntB + nt2) * 16 + lrow) * 128 + ks * 32 + lquad * 8];
            acc = __builtin_amdgcn_mfma_f32_16x16x32_bf16(afrag[ks], bfr, acc, 0, 0, 0);
        }
#pragma unroll
        for (int i = 0; i < 4; ++i) hreg[nt2][i] = acc[i];
    }
#pragma unroll
    for (int nt2 = 0; nt2 < 4; ++nt2) {
        int col = (ntB + nt2) * 16 + lrow;
        float bb = b1l[col];
#pragma unroll
        for (int i = 0; i < 4; ++i) {
            int row = rt * 16 + lquad * 4 + i;
            At[row * ATS + col] = f2bf(fmaxf(hreg[nt2][i] * dn[row] + bb, 0.f));
        }
    }
    __syncthreads();   // cross-wave: GEMM2 reads h cols written by nt-half peer

    // ---- GEMM2 on waves 0/2 (row-tile wv>>1) ----
    if ((wv & 1) == 0) {
        short8 hf[4];
#pragma unroll
        for (int ks = 0; ks < 4; ++ks)
            hf[ks] = *(const short8*)&At[(rt * 16 + lrow) * ATS + ks * 32 + lquad * 8];
#pragma unroll
        for (int nt = 0; nt < 3; ++nt) {
            f32x4 acc = {0.f, 0.f, 0.f, 0.f};
#pragma unroll
            for (int ks = 0; ks < 4; ++ks) {
                short8 bfr = *(const short8*)&w2t[(nt * 16 + lrow) * 128 + ks * 32 + lquad * 8];
                acc = __builtin_amdgcn_mfma_f32_16x16x32_bf16(hf[ks], bfr, acc, 0, 0, 0);
            }
            int col = nt * 16 + lrow;
            if (col < NC) {
#pragma unroll
                for (int i = 0; i < 4; ++i) {
                    int row = rt * 16 + lquad * 4 + i;
                    int grow = r0 + row;
                    if (grow < NN)
                        hwb[(size_t)grow * HPAD + col] = f2bf(acc[i] * sn[row]);
                }
            }
        }
    }
}

// one wave per node, hwb rows padded to 128 B. lane = g*8+j (g<8, j<8):
// 8 edge slots per step, uint4 reads; predicated 32-edge batches.
__global__ __launch_bounds__(256) void gather2_kernel(const int* __restrict__ row_beg,
                                                      const int* __restrict__ row_end,
                                                      const int* __restrict__ esrc,
                                                      const unsigned short* __restrict__ hwb,
                                                      const float* __restrict__ dst_norm,
                                                      const float* __restrict__ b2,
                                                      float* __restrict__ out) {
    int node = (blockIdx.x * blockDim.x + threadIdx.x) >> 6;
    int lane = threadIdx.x & 63;
    if (node >= NN) return;
    int beg = __builtin_amdgcn_readfirstlane(row_beg[node]);
    int end = __builtin_amdgcn_readfirstlane(row_end[node]);
    const int g = lane >> 3;          // edge slot 0..7
    const int j = lane & 7;           // uint4 index within 128 B row
    float a0 = 0.f, a1 = 0.f, a2 = 0.f, a3 = 0.f;
    float a4 = 0.f, a5 = 0.f, a6 = 0.f, a7 = 0.f;
    for (int e = beg; e < end; e += 32) {
        const int rem = end - e;
        int s[4];
        float m[4];
#pragma unroll
        for (int q = 0; q < 4; ++q) {
            int slot = q * 8 + g;
            bool v = (slot < rem);
            s[q] = esrc[v ? (e + slot) : beg];
            m[q] = v ? 1.f : 0.f;
        }
        uint4 u[4];
#pragma unroll
        for (int q = 0; q < 4; ++q)
            u[q] = ((const uint4*)(hwb + (size_t)s[q] * HPAD))[j];
#pragma unroll
        for (int q = 0; q < 4; ++q) {
            a0 += bflo(u[q].x) * m[q]; a1 += bfhi(u[q].x) * m[q];
            a2 += bflo(u[q].y) * m[q]; a3 += bfhi(u[q].y) * m[q];
            a4 += bflo(u[q].z) * m[q]; a5 += bfhi(u[q].z) * m[q];
            a6 += bflo(u[q].w) * m[q]; a7 += bfhi(u[q].w) * m[q];
        }
    }
    // reduce over the 8 g-groups (same j): lanes l <- l+32, l+16, l+8
    a0 += __shfl_down(a0, 32); a1 += __shfl_down(a1, 32);
    a2 += __shfl_down(a2, 32); a3 += __shfl_down(a3, 32);
    a4 += __shfl_down(a4, 32); a5 += __shfl_down(a5, 32);
    a6 += __shfl_down(a6, 32); a7 += __shfl_down(a7, 32);
    a0 += __shfl_down(a0, 16); a1 += __shfl_down(a1, 16);
    a2 += __shfl_down(a2, 16); a3 += __shfl_down(a3, 16);
    a4 += __shfl_down(a4, 16); a5 += __shfl_down(a5, 16);
    a6 += __shfl_down(a6, 16); a7 += __shfl_down(a7, 16);
    a0 += __shfl_down(a0, 8);  a1 += __shfl_down(a1, 8);
    a2 += __shfl_down(a2, 8);  a3 += __shfl_down(a3, 8);
    a4 += __shfl_down(a4, 8);  a5 += __shfl_down(a5, 8);
    a6 += __shfl_down(a6, 8);  a7 += __shfl_down(a7, 8);
    if (lane < 5) {                    // j = lane, g == 0: cols 8j..8j+7
        float dnv = dst_norm[node];
        float4 bb0 = ((const float4*)b2)[2 * lane];
        float4 bb1 = ((const float4*)b2)[2 * lane + 1];
        float4 o0, o1;
        o0.x = a0 * dnv + bb0.x;
        o0.y = a1 * dnv + bb0.y;
        o0.z = a2 * dnv + bb0.z;
        o0.w = a3 * dnv + bb0.w;
        o1.x = a4 * dnv + bb1.x;
        o1.y = a5 * dnv + bb1.y;
        o1.z = a6 * dnv + bb1.z;
        o1.w = a7 * dnv + bb1.w;
        float4* op = (float4*)(out + (size_t)node * NC);
        op[2 * lane]     = o0;
        op[2 * lane + 1] = o1;
    }
}

extern "C" void kernel_launch(void* const* d_in, const int* in_sizes, int n_in,
                              void* d_out, int out_size, void* d_ws, size_t ws_size,
                              hipStream_t stream) {
    const float* x   = (const float*)d_in[0];
    const float* W1  = (const float*)d_in[1];
    const float* b1  = (const float*)d_in[2];
    const float* W2  = (const float*)d_in[3];
    const float* b2  = (const float*)d_in[4];
    const int*   src = (const int*)d_in[5];
    const int*   dst = (const int*)d_in[6];
    float* out = (float*)d_out;

    // workspace (4B units):
    // srcn[NN] | curDg[256] | curSg[256] | row_beg[NN] | row_end[NN] |
    // dstn[NN] | esrc[NBK*CAPB] | pad | xh[NN*64] | w1t[8192] | w2t[3072] |
    // hwb[NN*32]  (bf16 NN x 64)
    float* srcn = (float*)d_ws;
    int* curDg = (int*)(srcn + NN);
    int* curSg = curDg + 256;
    int* row_beg = curSg + 256;
    int* row_end = row_beg + NN;
    float* dstn  = (float*)(row_end + NN);
    int* esrc    = (int*)(dstn + NN);
    size_t ofs = (size_t)NN + 512 + 3 * (size_t)NN + (size_t)NBK * CAPB;
    ofs = (ofs + 3) & ~(size_t)3;                 // 16B align
    unsigned short* xh   = (unsigned short*)((float*)d_ws + ofs);
    unsigned short* w1t  = xh + (size_t)NN * INF;
    unsigned short* w2t  = w1t + 128 * 128;
    unsigned short* hwb  = w2t + 48 * 128;

    // edge-record scratch in d_out (12 MB of 16 MB) — dead before gather2 writes
    int* epartsD = (int*)d_out;                                 // 8.03 MB
    unsigned short* epartsS = (unsigned short*)(epartsD + (size_t)NBK * CAPB);  // 4.01 MB

    hipMemsetAsync(curDg, 0, 512 * sizeof(int), stream);   // curDg | curSg

    part_kernel<<<PBLK, 256, 0, stream>>>(src, dst, curDg, curSg,
                                          epartsD, epartsS);
    pass2conv_kernel<<<NBK + CVB4 + 2, 1024, 0, stream>>>(epartsD, epartsS,
                                                          curDg, curSg,
                                                          row_beg, row_end, esrc,
                                                          srcn, dstn,
                                                          x, xh, W1, W2, w1t, w2t);
    fused_kernel<<<(NN + 31) / 32, 256, 0, stream>>>(row_beg, row_end, esrc, xh,
                                                     srcn, w1t, w2t, b1, dstn, hwb);
    gather2_kernel<<<(NN * 64 + 255) / 256, 256, 0, stream>>>(row_beg, row_end,
                                                              esrc, hwb,
                                                              dstn, b2, out);
}